// Round 5
// baseline (357.213 us; speedup 1.0000x reference)
//
#include <hip/hip_runtime.h>

// Problem constants (match reference)
#define BATCH    64
#define HEIGHT   512
#define WIDTH    512
#define CHAN     3
#define PATCH    8
#define NPH      64
#define NPW      64
#define NP_TOT   4096          // NPH*NPW
#define NUM_MASK 3072          // 0.75 * NP_TOT

#define PER_IMG4 (HEIGHT * WIDTH * CHAN / 4)   // 196608 float4 per image
#define PER_ROW4 (WIDTH * CHAN / 4)            // 384 float4 per row
#define TOTAL4   (BATCH * PER_IMG4)            // 12,582,912 float4 total
#define VPT      8                             // float4 per thread (MLP depth)
#define TILE4    (256 * VPT)                   // 2048 float4 per block

// Native vector type for nontemporal builtins (HIP's float4 wrapper is
// rejected by __builtin_nontemporal_*; same global_load/store_dwordx4 + nt).
typedef float f32x4 __attribute__((ext_vector_type(4)));

// Kernel 1 (merged init+scatter): one block per image.
//  - 256 threads vector-init the image's 4096-byte mask region to 1
//  - __syncthreads()
//  - each thread scatters 12 zero bytes at the image's masked patch indices.
// Indices within an image are a permutation prefix (distinct) -> race-free.
// (d_ws is re-poisoned before every launch, so init must run each call.)
__global__ __launch_bounds__(256) void rm_build_mask(
        const int* __restrict__ mask_indices,
        unsigned char* __restrict__ mask) {
    const int b = blockIdx.x;
    const int t = threadIdx.x;

    uint4 ones = make_uint4(0x01010101u, 0x01010101u, 0x01010101u, 0x01010101u);
    reinterpret_cast<uint4*>(mask + b * NP_TOT)[t] = ones;
    __syncthreads();

    const int* __restrict__ idx = mask_indices + b * NUM_MASK;
    unsigned char* __restrict__ m = mask + b * NP_TOT;
#pragma unroll
    for (int j = 0; j < 12; ++j) {
        m[idx[t + j * 256]] = (unsigned char)0;
    }
}

// Kernel 2: out = in * mask, VPT=8 float4 per thread, batched for MLP:
//   loop A: 8 mask-byte lookups
//   loop B: 8 independent exec-masked nt loads (in flight simultaneously)
//   loop C: 8 nt stores
// 75% of patches masked -> those lanes write zeros WITHOUT reading input
// (exec-masked global_load_dwordx4 fetches only active lanes' sectors:
// each 96 B unmasked patch row-segment touches exactly two 64 B sectors,
// so reads ~ 25% * 4/3 of the input ~ 67 MB). A patch covers 24 contiguous
// floats per row (6 float4), so each aligned float4 lies in exactly one
// patch -> one byte-mask lookup per 16 B (L1-broadcast across the wave).
// Non-temporal hints keep the 384 MB stream from thrashing the caches
// holding the 256 KB mask.
__global__ __launch_bounds__(256) void rm_apply_mask(
        const f32x4* __restrict__ in,
        f32x4*       __restrict__ out,
        const unsigned char* __restrict__ mask) {
    const int base = blockIdx.x * TILE4 + threadIdx.x;

    unsigned char m[VPT];
#pragma unroll
    for (int j = 0; j < VPT; ++j) {
        const int tid = base + j * 256;
        const int b   = tid / PER_IMG4;
        const int r   = tid - b * PER_IMG4;
        const int y   = r / PER_ROW4;
        const int x4  = r - y * PER_ROW4;
        const int px  = x4 / 6;          // 6 float4 per patch along x
        const int py  = y >> 3;          // 8 rows per patch
        m[j] = mask[b * NP_TOT + (py << 6) + px];
    }

    f32x4 v[VPT];
#pragma unroll
    for (int j = 0; j < VPT; ++j) {
        v[j] = (f32x4)(0.f, 0.f, 0.f, 0.f);
        if (m[j]) v[j] = __builtin_nontemporal_load(&in[base + j * 256]);
    }

#pragma unroll
    for (int j = 0; j < VPT; ++j) {
        __builtin_nontemporal_store(v[j], &out[base + j * 256]);
    }
}

extern "C" void kernel_launch(void* const* d_in, const int* in_sizes, int n_in,
                              void* d_out, int out_size, void* d_ws, size_t ws_size,
                              hipStream_t stream) {
    const float* images       = (const float*)d_in[0];
    const int*   mask_indices = (const int*)d_in[1];
    float*       out          = (float*)d_out;
    unsigned char* mask       = (unsigned char*)d_ws;   // 256 KB used

    // 1) mask := 1 then mask[b, idx] := 0   (one block per image)
    rm_build_mask<<<BATCH, 256, 0, stream>>>(mask_indices, mask);

    // 2) out = in * mask   (TOTAL4 = 6144 * TILE4 exactly)
    rm_apply_mask<<<TOTAL4 / TILE4, 256, 0, stream>>>(
        (const f32x4*)images, (f32x4*)out, mask);
}

// Round 6
// 307.182 us; speedup vs baseline: 1.1629x; 1.1629x over previous
//
#include <hip/hip_runtime.h>

// Problem constants (match reference)
#define BATCH    64
#define HEIGHT   512
#define WIDTH    512
#define CHAN     3
#define PATCH    8
#define NPH      64
#define NPW      64
#define NP_TOT   4096          // NPH*NPW
#define NUM_MASK 3072          // 0.75 * NP_TOT

#define PER_IMG4 (HEIGHT * WIDTH * CHAN / 4)   // 196608 float4 per image
#define PER_ROW4 (WIDTH * CHAN / 4)            // 384 float4 per row
#define TOTAL4   (BATCH * PER_IMG4)            // 12,582,912 float4 total
#define VPT      4                             // float4 per thread (MLP depth)
                                               // NOTE: VPT=8 measured 357 us
                                               // (exec-mask chains + reg
                                               // pressure) -- keep 4.
#define TILE4    (256 * VPT)                   // 1024 float4 per block

// Native vector type for nontemporal builtins (HIP's float4 wrapper is
// rejected by __builtin_nontemporal_*; same global_load/store_dwordx4 + nt).
typedef float f32x4 __attribute__((ext_vector_type(4)));

// Kernel 1 (merged init+scatter): one block per image.
//  - 256 threads vector-init the image's 4096-byte mask region to 1
//  - __syncthreads()
//  - each thread scatters 12 zero bytes at the image's masked patch indices.
// Indices within an image are a permutation prefix (distinct) -> race-free.
// (d_ws is re-poisoned before every launch, so init must run each call.)
__global__ __launch_bounds__(256) void rm_build_mask(
        const int* __restrict__ mask_indices,
        unsigned char* __restrict__ mask) {
    const int b = blockIdx.x;
    const int t = threadIdx.x;

    uint4 ones = make_uint4(0x01010101u, 0x01010101u, 0x01010101u, 0x01010101u);
    reinterpret_cast<uint4*>(mask + b * NP_TOT)[t] = ones;
    __syncthreads();

    const int* __restrict__ idx = mask_indices + b * NUM_MASK;
    unsigned char* __restrict__ m = mask + b * NP_TOT;
#pragma unroll
    for (int j = 0; j < 12; ++j) {
        m[idx[t + j * 256]] = (unsigned char)0;
    }
}

// Kernel 2: out = in * mask, VPT=4 float4 per thread, batched for MLP:
//   loop A: 4 mask-byte lookups
//   loop B: 4 independent exec-masked nt loads (in flight simultaneously)
//   loop C: 4 nt stores
// 75% of patches masked -> those lanes write zeros WITHOUT reading input
// (exec-masked global_load_dwordx4 fetches only active lanes' sectors:
// each 96 B unmasked patch row-segment touches exactly two 64 B sectors,
// so reads ~ 25% * 4/3 of the input ~ 67 MB). A patch covers 24 contiguous
// floats per row (6 float4), so each aligned float4 lies in exactly one
// patch -> one byte-mask lookup per 16 B (L1-broadcast across the wave).
// Non-temporal hints keep the 384 MB stream from thrashing the caches
// holding the 256 KB mask.
__global__ __launch_bounds__(256) void rm_apply_mask(
        const f32x4* __restrict__ in,
        f32x4*       __restrict__ out,
        const unsigned char* __restrict__ mask) {
    const int base = blockIdx.x * TILE4 + threadIdx.x;

    unsigned char m[VPT];
#pragma unroll
    for (int j = 0; j < VPT; ++j) {
        const int tid = base + j * 256;
        const int b   = tid / PER_IMG4;
        const int r   = tid - b * PER_IMG4;
        const int y   = r / PER_ROW4;
        const int x4  = r - y * PER_ROW4;
        const int px  = x4 / 6;          // 6 float4 per patch along x
        const int py  = y >> 3;          // 8 rows per patch
        m[j] = mask[b * NP_TOT + (py << 6) + px];
    }

    f32x4 v[VPT];
#pragma unroll
    for (int j = 0; j < VPT; ++j) {
        v[j] = (f32x4)(0.f, 0.f, 0.f, 0.f);
        if (m[j]) v[j] = __builtin_nontemporal_load(&in[base + j * 256]);
    }

#pragma unroll
    for (int j = 0; j < VPT; ++j) {
        __builtin_nontemporal_store(v[j], &out[base + j * 256]);
    }
}

extern "C" void kernel_launch(void* const* d_in, const int* in_sizes, int n_in,
                              void* d_out, int out_size, void* d_ws, size_t ws_size,
                              hipStream_t stream) {
    const float* images       = (const float*)d_in[0];
    const int*   mask_indices = (const int*)d_in[1];
    float*       out          = (float*)d_out;
    unsigned char* mask       = (unsigned char*)d_ws;   // 256 KB used

    // 1) mask := 1 then mask[b, idx] := 0   (one block per image)
    rm_build_mask<<<BATCH, 256, 0, stream>>>(mask_indices, mask);

    // 2) out = in * mask   (TOTAL4 = 12288 * TILE4 exactly)
    rm_apply_mask<<<TOTAL4 / TILE4, 256, 0, stream>>>(
        (const f32x4*)images, (f32x4*)out, mask);
}